// Round 1
// baseline (408.464 us; speedup 1.0000x reference)
//
#include <hip/hip_runtime.h>
#include <stdint.h>

// SelfAttentionV3: out = softmax(mask(QK^T/32)) V with Q=Xq Wq+bq etc.
// B=8, S=2048, D=1024. All GEMMs in bf16 MFMA (fp32 accum).
//
// ws layout (bytes):
//   [0,                32M)  q_bf16  [16384][1024]
//   [32M,              64M)  k_bf16  [16384][1024]
//   [64M,              96M)  vT_bf16 [8][1024][2048]
//   [96M,             192M)  A_bf16  (converted inputs q,k,v)     (dead after projections)
//   [192M,            198M)  WT_bf16 (transposed weights)         (dead after projections)
//   [96M,             224M)  scores fp32 [8][2048][2048]  (overlays A/WT region)
// softmax writes P bf16 in-place into the first half of each fp32 score row.
// Total ws needed: 234,881,024 bytes.

typedef unsigned short u16;
typedef __attribute__((ext_vector_type(8))) short short8;
typedef __attribute__((ext_vector_type(4))) float f32x4;

#define BM 128
#define BN 128
#define BK 32

__device__ __forceinline__ u16 f2bf(float x) {
  unsigned u = __float_as_uint(x);
  return (u16)((u + 0x7FFFu + ((u >> 16) & 1u)) >> 16);  // RNE
}

__device__ __forceinline__ void stage16(const void* g, void* l) {
  const __attribute__((address_space(1))) uint32_t* gp =
      (const __attribute__((address_space(1))) uint32_t*)(uintptr_t)g;
  __attribute__((address_space(3))) uint32_t* lp =
      (__attribute__((address_space(3))) uint32_t*)(uintptr_t)l;
  __builtin_amdgcn_global_load_lds(gp, lp, 16, 0, 0);
}

// fp32 -> bf16 elementwise convert (vectorized)
__global__ __launch_bounds__(256) void cvt(const float4* __restrict__ in,
                                           ushort4* __restrict__ out, int n4) {
  int stride = gridDim.x * blockDim.x;
  for (int i = blockIdx.x * blockDim.x + threadIdx.x; i < n4; i += stride) {
    float4 f = in[i];
    ushort4 o;
    o.x = f2bf(f.x); o.y = f2bf(f.y); o.z = f2bf(f.z); o.w = f2bf(f.w);
    out[i] = o;
  }
}

// W [1024][1024] fp32 -> WT [1024][1024] bf16 transposed (WT[n][d] = W[d][n])
__global__ __launch_bounds__(256) void wtrans(const float* __restrict__ W,
                                              u16* __restrict__ WT) {
  __shared__ float tile[32][33];
  const int tx = threadIdx.x, ty = threadIdx.y;  // 32 x 8
  const int d0 = blockIdx.y * 32, n0 = blockIdx.x * 32;
#pragma unroll
  for (int i = 0; i < 4; ++i)
    tile[ty + 8 * i][tx] = W[(size_t)(d0 + ty + 8 * i) * 1024 + n0 + tx];
  __syncthreads();
#pragma unroll
  for (int i = 0; i < 4; ++i)
    WT[(size_t)(n0 + ty + 8 * i) * 1024 + d0 + tx] = f2bf(tile[tx][ty + 8 * i]);
}

// C = A * B^T where A is [M][K] (row stride lda), B is [N][K] (row stride ldb),
// both bf16, K-contiguous. 128x128 tile, BK=32, 4 waves (2x2), 16x16x32 MFMA.
// MODE 0: bf16 out row-major + bias        (q,k projection)
// MODE 1: bf16 out transposed vT[b][n][s] + bias (v projection; M rows = b*2048+s)
// MODE 2: fp32 out row-major, * 1/32       (scores)
// MODE 3: fp32 out row-major               (PV -> d_out)
template <int MODE>
__global__ __launch_bounds__(256, 2) void gemm_bt(
    const u16* __restrict__ A, const u16* __restrict__ B,
    const float* __restrict__ bias, void* __restrict__ C,
    int K, int lda, int ldb, int ldc,
    size_t Az, size_t Bz, size_t Cz) {
  __shared__ __attribute__((aligned(16))) u16 lsA[BM * BK];
  __shared__ __attribute__((aligned(16))) u16 lsB[BN * BK];
  const int tid = threadIdx.x;
  const int lane = tid & 63;
  const int w = tid >> 6;
  const int wr = w >> 1, wc = w & 1;
  const int bm = blockIdx.x, bn = blockIdx.y, z = blockIdx.z;
  A += (size_t)z * Az;
  B += (size_t)z * Bz;

  // staging: wave w stages rows [w*32, w*32+32) of each tile; per issue a wave
  // writes 64 lanes * 16B = 16 rows (4 lanes/row, 16B each).
  const int srow = lane >> 2;
  const int scol = (lane & 3) * 8;
  const u16* Ag0 = A + (size_t)(bm * BM + w * 32 + srow) * lda + scol;
  const u16* Ag1 = Ag0 + (size_t)16 * lda;
  const u16* Bg0 = B + (size_t)(bn * BN + w * 32 + srow) * ldb + scol;
  const u16* Bg1 = Bg0 + (size_t)16 * ldb;
  u16* lA0 = &lsA[(w * 32) * BK];
  u16* lA1 = &lsA[(w * 32 + 16) * BK];
  u16* lB0 = &lsB[(w * 32) * BK];
  u16* lB1 = &lsB[(w * 32 + 16) * BK];

  const int arow = wr * 64 + (lane & 15);  // + m*16
  const int brow = wc * 64 + (lane & 15);  // + n*16
  const int ko = (lane >> 4) * 8;          // k-offset of this lane's 8 elems

  f32x4 acc[4][4] = {};

  for (int k0 = 0; k0 < K; k0 += BK) {
    stage16(Ag0 + k0, lA0);
    stage16(Ag1 + k0, lA1);
    stage16(Bg0 + k0, lB0);
    stage16(Bg1 + k0, lB1);
    __syncthreads();  // drains vmcnt before barrier
    short8 af[4], bfr[4];
#pragma unroll
    for (int m = 0; m < 4; ++m)
      af[m] = *(const short8*)&lsA[(arow + m * 16) * BK + ko];
#pragma unroll
    for (int n = 0; n < 4; ++n)
      bfr[n] = *(const short8*)&lsB[(brow + n * 16) * BK + ko];
#pragma unroll
    for (int m = 0; m < 4; ++m)
#pragma unroll
      for (int n = 0; n < 4; ++n)
        acc[m][n] =
            __builtin_amdgcn_mfma_f32_16x16x32_bf16(af[m], bfr[n], acc[m][n], 0, 0, 0);
    __syncthreads();
  }

  // D layout (verified): col = lane&15, row = (lane>>4)*4 + j
  const int col0 = bn * BN + wc * 64 + (lane & 15);
  const int row0 = bm * BM + wr * 64 + ((lane >> 4) << 2);

  if constexpr (MODE == 0) {
    u16* Cb = (u16*)C;
#pragma unroll
    for (int m = 0; m < 4; ++m)
#pragma unroll
      for (int n = 0; n < 4; ++n) {
        const int c = col0 + n * 16;
        const float bv = bias[c];
#pragma unroll
        for (int j = 0; j < 4; ++j)
          Cb[(size_t)(row0 + m * 16 + j) * ldc + c] = f2bf(acc[m][n][j] + bv);
      }
  } else if constexpr (MODE == 1) {
    u16* Cb = (u16*)C;  // vT [8][1024][2048]
#pragma unroll
    for (int m = 0; m < 4; ++m) {
      const int s0 = row0 + m * 16;       // global seq-row in [0,16384)
      const int b = s0 >> 11;             // batch
      const int s = s0 & 2047;            // seq within batch (4 consecutive j)
#pragma unroll
      for (int n = 0; n < 4; ++n) {
        const int c = col0 + n * 16;
        const float bv = bias[c];
        ushort4 o;
        o.x = f2bf(acc[m][n][0] + bv);
        o.y = f2bf(acc[m][n][1] + bv);
        o.z = f2bf(acc[m][n][2] + bv);
        o.w = f2bf(acc[m][n][3] + bv);
        *(ushort4*)&Cb[((size_t)b * 1024 + c) * 2048 + s] = o;
      }
    }
  } else {
    float* Cb = (float*)C + (size_t)z * Cz;
    const float sc = (MODE == 2) ? 0.03125f : 1.0f;  // 1/sqrt(1024)
#pragma unroll
    for (int m = 0; m < 4; ++m)
#pragma unroll
      for (int n = 0; n < 4; ++n) {
        const int c = col0 + n * 16;
#pragma unroll
        for (int j = 0; j < 4; ++j)
          Cb[(size_t)(row0 + m * 16 + j) * ldc + c] = acc[m][n][j] * sc;
      }
  }
}

// Masked row softmax over fp32 scores [2048]; writes P as bf16 in-place into the
// first 4096 bytes of the row. mask[row]==0 -> uniform 1/2048 (reference: all
// scores become exactly -1e9 in fp32 -> uniform softmax). Else masked cols -> 0.
__global__ __launch_bounds__(256) void softmax_mask(float* __restrict__ scores,
                                                    const int* __restrict__ mask) {
  const int row = blockIdx.x, b = blockIdx.y;
  const int t = threadIdx.x, lane = t & 63, w = t >> 6;
  float* sc = scores + ((size_t)(b * 2048 + row) << 11);
  u16* pout = (u16*)sc;
  const int mrow = mask[b * 2048 + row];
  if (mrow == 0) {
    const u16 pv = f2bf(1.0f / 2048.0f);
    ushort4 o;
    o.x = o.y = o.z = o.w = pv;
    *(ushort4*)&pout[t * 8] = o;
    *(ushort4*)&pout[t * 8 + 4] = o;
    return;
  }
  const float4 x0 = ((const float4*)sc)[t * 2];
  const float4 x1 = ((const float4*)sc)[t * 2 + 1];
  const int4 m0 = ((const int4*)(mask + b * 2048))[t * 2];
  const int4 m1 = ((const int4*)(mask + b * 2048))[t * 2 + 1];
  float v[8] = {x0.x, x0.y, x0.z, x0.w, x1.x, x1.y, x1.z, x1.w};
  const int mm[8] = {m0.x, m0.y, m0.z, m0.w, m1.x, m1.y, m1.z, m1.w};
  float lmax = -3.0e38f;
#pragma unroll
  for (int i = 0; i < 8; ++i)
    if (mm[i]) lmax = fmaxf(lmax, v[i]);
#pragma unroll
  for (int off = 32; off >= 1; off >>= 1) lmax = fmaxf(lmax, __shfl_xor(lmax, off));
  __shared__ float red[8];
  if (lane == 0) red[w] = lmax;
  __syncthreads();
  const float bmax = fmaxf(fmaxf(red[0], red[1]), fmaxf(red[2], red[3]));
  float e[8];
  float lsum = 0.f;
#pragma unroll
  for (int i = 0; i < 8; ++i) {
    e[i] = mm[i] ? __expf(v[i] - bmax) : 0.f;
    lsum += e[i];
  }
#pragma unroll
  for (int off = 32; off >= 1; off >>= 1) lsum += __shfl_xor(lsum, off);
  if (lane == 0) red[4 + w] = lsum;
  __syncthreads();
  const float inv = 1.0f / ((red[4] + red[5]) + (red[6] + red[7]));
  ushort4 o0, o1;
  o0.x = f2bf(e[0] * inv); o0.y = f2bf(e[1] * inv);
  o0.z = f2bf(e[2] * inv); o0.w = f2bf(e[3] * inv);
  o1.x = f2bf(e[4] * inv); o1.y = f2bf(e[5] * inv);
  o1.z = f2bf(e[6] * inv); o1.w = f2bf(e[7] * inv);
  *(ushort4*)&pout[t * 8] = o0;
  *(ushort4*)&pout[t * 8 + 4] = o1;
}

extern "C" void kernel_launch(void* const* d_in, const int* in_sizes, int n_in,
                              void* d_out, int out_size, void* d_ws, size_t ws_size,
                              hipStream_t stream) {
  const float* in_q = (const float*)d_in[0];
  const float* in_k = (const float*)d_in[1];
  const float* in_v = (const float*)d_in[2];
  const int* mask = (const int*)d_in[3];
  const float* Wq = (const float*)d_in[4];
  const float* bq = (const float*)d_in[5];
  const float* Wk = (const float*)d_in[6];
  const float* bk = (const float*)d_in[7];
  const float* Wv = (const float*)d_in[8];
  const float* bv = (const float*)d_in[9];

  char* ws = (char*)d_ws;
  const size_t SZ = (size_t)16384 * 1024 * 2;  // 32M bytes per bf16 [16384][1024]
  u16* qb = (u16*)(ws);
  u16* kb = (u16*)(ws + SZ);
  u16* vT = (u16*)(ws + 2 * SZ);
  u16* Aq = (u16*)(ws + 3 * SZ);
  u16* Ak = (u16*)(ws + 4 * SZ);
  u16* Av = (u16*)(ws + 5 * SZ);
  u16* WqT = (u16*)(ws + 6 * SZ);
  u16* WkT = WqT + 1024 * 1024;
  u16* WvT = WkT + 1024 * 1024;
  float* scores = (float*)(ws + 3 * SZ);  // overlays Aq/Ak/Av/WT after projections

  // 1) converts
  const int n4 = 16384 * 1024 / 4;
  cvt<<<2048, 256, 0, stream>>>((const float4*)in_q, (ushort4*)Aq, n4);
  cvt<<<2048, 256, 0, stream>>>((const float4*)in_k, (ushort4*)Ak, n4);
  cvt<<<2048, 256, 0, stream>>>((const float4*)in_v, (ushort4*)Av, n4);
  dim3 wtb(32, 8);
  wtrans<<<dim3(32, 32), wtb, 0, stream>>>(Wq, WqT);
  wtrans<<<dim3(32, 32), wtb, 0, stream>>>(Wk, WkT);
  wtrans<<<dim3(32, 32), wtb, 0, stream>>>(Wv, WvT);

  // 2) projections: [16384x1024] = [16384x1024] x [1024x1024]^T
  gemm_bt<0><<<dim3(128, 8, 1), 256, 0, stream>>>(Aq, WqT, bq, qb, 1024, 1024, 1024,
                                                  1024, 0, 0, 0);
  gemm_bt<0><<<dim3(128, 8, 1), 256, 0, stream>>>(Ak, WkT, bk, kb, 1024, 1024, 1024,
                                                  1024, 0, 0, 0);
  gemm_bt<1><<<dim3(128, 8, 1), 256, 0, stream>>>(Av, WvT, bv, vT, 1024, 1024, 1024,
                                                  2048, 0, 0, 0);

  // 3) scores[b] = q[b] k[b]^T / 32   (per batch, fp32 out)
  gemm_bt<2><<<dim3(16, 16, 8), 256, 0, stream>>>(
      qb, kb, nullptr, scores, 1024, 1024, 1024, 2048,
      (size_t)2048 * 1024, (size_t)2048 * 1024, (size_t)2048 * 2048);

  // 4) masked softmax -> P bf16 in-place (row stride stays 8192 B = 4096 elems)
  softmax_mask<<<dim3(2048, 8), 256, 0, stream>>>(scores, mask);

  // 5) out[b] = P[b] vT[b]^T   (A = P bf16 lda 4096, B = vT [1024][2048])
  gemm_bt<3><<<dim3(16, 8, 8), 256, 0, stream>>>(
      (const u16*)scores, vT, nullptr, d_out, 2048, 4096, 2048, 1024,
      (size_t)2048 * 4096, (size_t)1024 * 2048, (size_t)2048 * 1024);
}